// Round 12
// baseline (643.355 us; speedup 1.0000x reference)
//
#include <hip/hip_runtime.h>

#define D_   32
#define H_   256
#define W_   256
#define HW_  (H_ * W_)
#define DHW_ (D_ * H_ * W_)   // 2097152
#define V_   40000
#define CIN  16
#define COUT 32
#define P_   32
#define EPS_ 1e-5f

#define TD 2
#define TH 8
#define TW 32
#define NTX (W_ / TW)          // 8
#define NTY (H_ / TH)          // 32
#define NTZ (D_ / TD)          // 16
#define NT  (NTX * NTY * NTZ)  // 4096 tiles
#define TPOS (TD * TH * TW)    // 512
#define OH 8                   // channels per quarter
#define NQ (COUT / OH)         // 4
#define TROW 9                 // padded LDS row stride (odd -> conflict-free strided reads)
#define TCT 512                // threads per tile_conv block (8 waves)
#define SSLOT 64               // stats de-contention slots per channel
#define TAPC 640               // LDS-staged taps per tile (mean ~257; overflow reads global)
#define WTN  (NQ * 27 * 4 * OH)            // 3456 transpose items
#define WTBLK ((WTN + 255) / 256)          // 14 transpose blocks
#define CBLK  (V_ * 8 / 256)               // 1250 count/fill blocks (V*8 = 320000 exact)
#define FPBLK (V_ * CIN / 256)             // 2500 featpack blocks (V*16 = 640000 exact)

// ---------- K1: fused prep: 8x-parallel tap-count | weight transpose | 16x featpack ----------
__global__ void prep_kernel(const int* __restrict__ idxs, int* __restrict__ tapcnt,
                            const float* __restrict__ conv_w, float4* __restrict__ wt4,
                            const float* __restrict__ vox, float* __restrict__ feats) {
    int b = blockIdx.x;
    int t = threadIdx.x;
    if (b < CBLK) {
        // role A: tap count, one thread per (voxel, region-octant)
        int idx = b * 256 + t;
        int v = idx >> 3, r = idx & 7;
        int w = idxs[3 * v], h = idxs[3 * v + 1], d = idxs[3 * v + 2];
        if (!((unsigned)w < W_ && (unsigned)h < H_ && (unsigned)d < D_)) return;
        int dlo = max(d - 1, 0), dhi = min(d + 1, D_ - 1);
        int hlo = max(h - 1, 0), hhi = min(h + 1, H_ - 1);
        int wlo = max(w - 1, 0), whi = min(w + 1, W_ - 1);
        int tz = dlo / TD + ((r >> 2) & 1);
        int ty = hlo / TH + ((r >> 1) & 1);
        int tx = wlo / TW + (r & 1);
        if (tz > dhi / TD || ty > hhi / TH || tx > whi / TW) return;
        int zl = max(dlo, tz * TD), zh = min(dhi, tz * TD + TD - 1);
        int yl = max(hlo, ty * TH), yh = min(hhi, ty * TH + TH - 1);
        int xl = max(wlo, tx * TW), xh = min(whi, tx * TW + TW - 1);
        int cnt = (zh - zl + 1) * (yh - yl + 1) * (xh - xl + 1);
        atomicAdd(&tapcnt[tz * NTY * NTX + ty * NTX + tx], cnt);
        return;
    }
    b -= CBLK;
    if (b < WTBLK) {
        // role B: weight transpose wt4[((q*27+k)*4+jj)*8+oo] = {conv_w[o][4jj+i][k]}
        int n = b * 256 + t;
        if (n < WTN) {
            int oo = n & 7;
            int jj = (n >> 3) & 3;
            int m  = n >> 5;            // quarter*27 + k
            int k  = m % 27;
            int quarter = m / 27;
            int o = quarter * OH + oo;
            float4 wv;
            wv.x = conv_w[(o * CIN + 4 * jj + 0) * 27 + k];
            wv.y = conv_w[(o * CIN + 4 * jj + 1) * 27 + k];
            wv.z = conv_w[(o * CIN + 4 * jj + 2) * 27 + k];
            wv.w = conv_w[(o * CIN + 4 * jj + 3) * 27 + k];
            wt4[n] = wv;
        }
        return;
    }
    b -= WTBLK;
    // role C: featpack, one thread per (v, channel): read 128 B contiguous, store 1 float.
    int idx = b * 256 + t;                 // = v*16 + c, in [0, V_*16)
    const float4* p = (const float4*)(vox + (size_t)idx * P_);
    float s = 0.f;
#pragma unroll
    for (int j = 0; j < P_ / 4; ++j) {
        float4 tv = p[j];
        s += tv.x + tv.y + tv.z + tv.w;
    }
    feats[idx] = s * (1.0f / (float)P_);
}

// ---------- K2: exclusive prefix over 4096 tiles ----------
__global__ void scan_kernel(const int* __restrict__ counts, int* __restrict__ starts,
                            int* __restrict__ cursor) {
    __shared__ int part[256];
    int t = threadIdx.x;
    int base = t * 16;
    int s = 0;
    for (int j = 0; j < 16; ++j) s += counts[base + j];
    part[t] = s;
    __syncthreads();
    for (int off = 1; off < 256; off <<= 1) {
        int val = part[t];
        int add = (t >= off) ? part[t - off] : 0;
        __syncthreads();
        part[t] = val + add;
        __syncthreads();
    }
    int run = (t > 0) ? part[t - 1] : 0;
    for (int j = 0; j < 16; ++j) {
        starts[base + j] = run;
        cursor[base + j] = run;
        run += counts[base + j];
    }
}

// ---------- K3: tap fill, one thread per (voxel, region-octant) ----------
// tap word = (v<<14) | (k<<9) | pos
__global__ void tap_fill_kernel(const int* __restrict__ idxs, int* __restrict__ cursor,
                                int* __restrict__ tapbuf) {
    int idx = blockIdx.x * 256 + threadIdx.x;
    int v = idx >> 3, r = idx & 7;
    int w = idxs[3 * v], h = idxs[3 * v + 1], d = idxs[3 * v + 2];
    if (!((unsigned)w < W_ && (unsigned)h < H_ && (unsigned)d < D_)) return;
    int dlo = max(d - 1, 0), dhi = min(d + 1, D_ - 1);
    int hlo = max(h - 1, 0), hhi = min(h + 1, H_ - 1);
    int wlo = max(w - 1, 0), whi = min(w + 1, W_ - 1);
    int tz = dlo / TD + ((r >> 2) & 1);
    int ty = hlo / TH + ((r >> 1) & 1);
    int tx = wlo / TW + (r & 1);
    if (tz > dhi / TD || ty > hhi / TH || tx > whi / TW) return;
    int zl = max(dlo, tz * TD), zh = min(dhi, tz * TD + TD - 1);
    int yl = max(hlo, ty * TH), yh = min(hhi, ty * TH + TH - 1);
    int xl = max(wlo, tx * TW), xh = min(whi, tx * TW + TW - 1);
    int cnt = (zh - zl + 1) * (yh - yl + 1) * (xh - xl + 1);
    int p = atomicAdd(&cursor[tz * NTY * NTX + ty * NTX + tx], cnt);
    for (int dq = zl; dq <= zh; ++dq)
        for (int hq = yl; hq <= yh; ++hq)
            for (int wq = xl; wq <= xh; ++wq) {
                int k = ((d - dq + 1) * 3 + (h - hq + 1)) * 3 + (w - wq + 1);
                int pos = ((dq & (TD - 1)) * TH + (hq & (TH - 1))) * TW + (wq & (TW - 1));
                tapbuf[p++] = (v << 14) | (k << 9) | pos;
            }
}

// ---------- K5: tile conv (BYTE-IDENTICAL to R9/R11 — control) ----------
__global__ void __launch_bounds__(TCT, 8) tile_conv_kernel(
    const float4* __restrict__ feats4, const float4* __restrict__ wt4,
    const int* __restrict__ tapstart, const int* __restrict__ tapcnt,
    const int* __restrict__ tapbuf, float* __restrict__ stats,
    float* __restrict__ out)
{
    __shared__ float  tile[TPOS * TROW];   // 18432 B
    __shared__ float4 wsm4[27 * 4 * OH];   // 13824 B, [k*32 + jj*8 + oo]
    __shared__ int    taps_l[TAPC];        //  2560 B (staging)
    __shared__ int    taps_s[TAPC];        //  2560 B (k-sorted)
    __shared__ int    khist[32];           //   128 B (hist -> cursor)
    __shared__ float  wsum[8][OH], wsq[8][OH];

    int t = threadIdx.x;
    int tile_id = blockIdx.x;
    int gs = tapstart[tile_id];
    int nt = tapcnt[tile_id];
    int tx = tile_id % NTX, ty = (tile_id / NTX) % NTY, tz = tile_id / (NTX * NTY);
    int w0 = tx * TW, h0 = ty * TH, d0 = tz * TD;
    int sl = tile_id & (SSLOT - 1);

    // stage tap list + counting-sort by k (done once, reused by all 4 quarters)
    int ntl = min(nt, TAPC);
    if (t < 32) khist[t] = 0;
    for (int j = t; j < ntl; j += TCT) taps_l[j] = tapbuf[gs + j];
    __syncthreads();
    for (int j = t; j < ntl; j += TCT)
        atomicAdd(&khist[(taps_l[j] >> 9) & 31], 1);
    __syncthreads();
    if (t < 64) {                           // wave-0 exclusive scan over 27 bins
        int x = (t < 27) ? khist[t] : 0;
        int orig = x;
#pragma unroll
        for (int off = 1; off < 32; off <<= 1) {
            int y = __shfl_up(x, off);
            if (t >= off) x += y;
        }
        if (t < 27) khist[t] = x - orig;    // becomes the scatter cursor
    }
    __syncthreads();
    for (int j = t; j < ntl; j += TCT) {
        int tap = taps_l[j];
        int p = atomicAdd(&khist[(tap >> 9) & 31], 1);
        taps_s[p] = tap;
    }
    __syncthreads();

    int oo = t & 7, slot = t >> 3;          // scatter + D1 mapping
    int wave = t >> 6, lane = t & 63;
    int wl = t & 31, rem = t >> 5;          // D2 mapping (rem 0..15)
    size_t outb = (size_t)(d0 + (rem >> 3)) * HW_ + (size_t)(h0 + (rem & 7)) * W_
                + (size_t)(w0 + wl);
    int posD = (rem * TW + wl) * TROW;

#pragma unroll
    for (int qq = 0; qq < NQ; ++qq) {
        int obase = qq * OH;
        // stage: zero tile + this quarter's weights (linear layout)
        for (int j = t; j < TPOS * TROW / 4; j += TCT)
            ((float4*)tile)[j] = make_float4(0, 0, 0, 0);
        for (int j = t; j < 27 * 4 * OH; j += TCT)
            wsm4[j] = wt4[qq * (27 * 4 * OH) + j];
        __syncthreads();

        // scatter over k-sorted taps: 4 b128 weight reads (mostly broadcast) +
        // 16 FMA + 1 ds_add per (tap, oo)
        for (int j = slot; j < nt; j += 64) {
            unsigned tap = (unsigned)((j < TAPC) ? taps_s[j] : tapbuf[gs + j]);
            int pos = tap & 511;
            int k = (tap >> 9) & 31;
            int src = tap >> 14;
            const float4* fp = feats4 + (size_t)src * 4;   // broadcast across 8 oo lanes
            float4 f0 = fp[0], f1 = fp[1], f2 = fp[2], f3 = fp[3];
            const float4* wp = &wsm4[k * 32 + oo];
            float4 q0 = wp[0], q1 = wp[8], q2 = wp[16], q3 = wp[24];
            float acc = q0.x * f0.x + q0.y * f0.y + q0.z * f0.z + q0.w * f0.w
                      + q1.x * f1.x + q1.y * f1.y + q1.z * f1.z + q1.w * f1.w
                      + q2.x * f2.x + q2.y * f2.y + q2.z * f2.z + q2.w * f2.w
                      + q3.x * f3.x + q3.y * f3.y + q3.z * f3.z + q3.w * f3.w;
            atomicAdd(&tile[pos * TROW + oo], acc);
        }
        __syncthreads();

        // D1: BN partial stats (8 LDS reads + 6 shuffles per thread)
        float s1 = 0.f, s2 = 0.f;
        for (int p = slot; p < TPOS; p += 64) {
            float sv = tile[p * TROW + oo];
            s1 += sv;
            s2 += sv * sv;
        }
        s1 += __shfl_xor(s1, 8);  s2 += __shfl_xor(s2, 8);
        s1 += __shfl_xor(s1, 16); s2 += __shfl_xor(s2, 16);
        s1 += __shfl_xor(s1, 32); s2 += __shfl_xor(s2, 32);
        if (lane < OH) { wsum[wave][lane] = s1; wsq[wave][lane] = s2; }

        // D2: write pre-norm output; stride-9 scalar LDS reads conflict-free
#pragma unroll
        for (int i = 0; i < OH; ++i)
            out[(size_t)(obase + i) * DHW_ + outb] = tile[posD + i];
        __syncthreads();

        if (t < OH) {
            float a = 0.f, b = 0.f;
#pragma unroll
            for (int wv = 0; wv < 8; ++wv) { a += wsum[wv][t]; b += wsq[wv][t]; }
            atomicAdd(&stats[(obase + t) * SSLOT + sl], a);
            atomicAdd(&stats[COUT * SSLOT + (obase + t) * SSLOT + sl], b);
        }
    }
}

// ---------- K6: finalize per-channel scale A and shift B (1 tiny block) ----------
__global__ void finalize_kernel(const float* __restrict__ stats,
                                const float* __restrict__ gamma,
                                const float* __restrict__ beta,
                                float* __restrict__ mi) {
    int t = threadIdx.x;
    if (t < COUT) {
        float m1 = 0.f, m2 = 0.f;
#pragma unroll 8
        for (int s = 0; s < SSLOT; ++s) {
            m1 += stats[t * SSLOT + s];
            m2 += stats[COUT * SSLOT + t * SSLOT + s];
        }
        float n = (float)DHW_;
        m1 /= n;
        m2 /= n;
        float var = fmaxf(m2 - m1 * m1, 0.f);
        float inv = rsqrtf(var + EPS_);
        float A = gamma[t] * inv;
        mi[t] = A;
        mi[COUT + t] = -m1 * A + beta[t];
    }
}

// ---------- K7: normalize + affine + ReLU — pure stream, max MLP ----------
// grid = COUT*512 = 16384 blocks; block = 256 thr x 4 float4 (16 KB/block).
// A,B uniform per block (c = bid>>9) -> scalar loads; no reduction prologue;
// 4 loads issued back-to-back before any use -> 4 outstanding vmem/thread.
__global__ void __launch_bounds__(256) norm_kernel(float* __restrict__ out,
                                                   const float* __restrict__ mi) {
    int bid = blockIdx.x;
    int c = bid >> 9;
    float A = mi[c], B = mi[COUT + c];
    float4* o4 = (float4*)out;
    int base = bid * 1024 + threadIdx.x;
    float4 x0 = o4[base];
    float4 x1 = o4[base + 256];
    float4 x2 = o4[base + 512];
    float4 x3 = o4[base + 768];
    x0.x = fmaxf(fmaf(x0.x, A, B), 0.f); x0.y = fmaxf(fmaf(x0.y, A, B), 0.f);
    x0.z = fmaxf(fmaf(x0.z, A, B), 0.f); x0.w = fmaxf(fmaf(x0.w, A, B), 0.f);
    x1.x = fmaxf(fmaf(x1.x, A, B), 0.f); x1.y = fmaxf(fmaf(x1.y, A, B), 0.f);
    x1.z = fmaxf(fmaf(x1.z, A, B), 0.f); x1.w = fmaxf(fmaf(x1.w, A, B), 0.f);
    x2.x = fmaxf(fmaf(x2.x, A, B), 0.f); x2.y = fmaxf(fmaf(x2.y, A, B), 0.f);
    x2.z = fmaxf(fmaf(x2.z, A, B), 0.f); x2.w = fmaxf(fmaf(x2.w, A, B), 0.f);
    x3.x = fmaxf(fmaf(x3.x, A, B), 0.f); x3.y = fmaxf(fmaf(x3.y, A, B), 0.f);
    x3.z = fmaxf(fmaf(x3.z, A, B), 0.f); x3.w = fmaxf(fmaf(x3.w, A, B), 0.f);
    o4[base]       = x0;
    o4[base + 256] = x1;
    o4[base + 512] = x2;
    o4[base + 768] = x3;
}

extern "C" void kernel_launch(void* const* d_in, const int* in_sizes, int n_in,
                              void* d_out, int out_size, void* d_ws, size_t ws_size,
                              hipStream_t stream) {
    const float* voxels  = (const float*)d_in[0];
    const int*   indices = (const int*)  d_in[1];
    const float* conv_w  = (const float*)d_in[2];
    const float* gamma   = (const float*)d_in[4];
    const float* beta    = (const float*)d_in[5];
    float* out = (float*)d_out;

    // Workspace layout: R4-proven extents (mi between stats and tapcnt; tapbuf last).
    float4* wt4      = (float4*)d_ws;                        // 3456 float4 (55,296 B)
    float*  stats    = (float*)(wt4 + WTN);                  // 2*COUT*SSLOT floats (16,384 B)
    float*  mi       = stats + 2 * COUT * SSLOT;             // 64 floats (256 B)
    int*    tapcnt   = (int*)(mi + 2 * COUT);                // NT ints
    int*    tapstart = tapcnt + NT;                          // NT ints
    int*    tapcur   = tapstart + NT;                        // NT ints
    float*  feats    = (float*)(tapcur + NT);                // V*16 floats (2.56 MB)
    int*    tapbuf   = (int*)(feats + (size_t)V_ * CIN);     // <= V*27 ints, prefix used

    hipMemsetAsync(stats, 0, 2 * COUT * SSLOT * sizeof(float), stream);
    hipMemsetAsync(tapcnt, 0, NT * sizeof(int), stream);

    prep_kernel<<<CBLK + WTBLK + FPBLK, 256, 0, stream>>>(indices, tapcnt, conv_w, wt4,
                                                          voxels, feats);
    scan_kernel<<<1, 256, 0, stream>>>(tapcnt, tapstart, tapcur);
    tap_fill_kernel<<<CBLK, 256, 0, stream>>>(indices, tapcur, tapbuf);

    tile_conv_kernel<<<NT, TCT, 0, stream>>>((const float4*)feats, wt4, tapstart, tapcnt,
                                             tapbuf, stats, out);

    finalize_kernel<<<1, 64, 0, stream>>>(stats, gamma, beta, mi);
    norm_kernel<<<COUT * 512, 256, 0, stream>>>(out, mi);
}